// Round 6
// baseline (388.191 us; speedup 1.0000x reference)
//
#include <hip/hip_runtime.h>
#include <math.h>

typedef short bf16x8 __attribute__((ext_vector_type(8)));
typedef float f32x16 __attribute__((ext_vector_type(16)));
typedef float f32x4 __attribute__((ext_vector_type(4)));
typedef unsigned u32x4 __attribute__((ext_vector_type(4)));

#define NF 4
#define D0 8
#define LPE_OUT 24

// ---------------- ws byte layout ----------------
#define LPE_OFF   17408
#define G0_OFF    816384
#define G1_OFF    817408
#define G2_OFF    821504
#define G3_OFF    837888
#define G4_OFF    903424
#define G5_OFF    1165568
#define G6_OFF    2214144
#define G7_OFF    6408448
#define WS_NEED   23185664ULL

// ---------- bf16 helpers ----------
__device__ __forceinline__ unsigned f2bf(float x) {
    unsigned u = __float_as_uint(x);
    u = u + 0x7fffu + ((u >> 16) & 1u);
    return u >> 16;
}
__device__ __forceinline__ unsigned pkbf(float a, float b) {
    return f2bf(a) | (f2bf(b) << 16);
}
__device__ __forceinline__ float bflo(unsigned u) { return __uint_as_float(u << 16); }
__device__ __forceinline__ float bfhi(unsigned u) { return __uint_as_float(u & 0xffff0000u); }
__device__ __forceinline__ bf16x8 mkfrag(unsigned w0, unsigned w1, unsigned w2, unsigned w3) {
    u32x4 u = { w0, w1, w2, w3 };
    return __builtin_bit_cast(bf16x8, u);
}

// ---------- weight prep (R3/R4-verified, unchanged) ----------
__global__ void prep_kernel(const float* __restrict__ w0, const float* __restrict__ b0,
                            const float* __restrict__ w1, const float* __restrict__ b1,
                            const float* __restrict__ w2, float* __restrict__ ws)
{
    int t = threadIdx.x;
    unsigned short* a0 = (unsigned short*)ws;
    unsigned short* a1 = a0 + 2048;
    unsigned short* a2 = a1 + 4096;
    float* b0c = (float*)(a2 + 2048);
    float* b1c = b0c + 64;

    for (int e = t; e < 2048; e += 256) {
        int tile = e >> 9, lane = (e >> 3) & 63, j = e & 7;
        int m = tile >> 1, ks = tile & 1;
        int row = m * 32 + (lane & 31);
        int k = ks * 16 + (lane >> 5) * 8 + j;
        float v = (k < 26) ? w0[k * 64 + row] : 0.f;
        a0[e] = (unsigned short)f2bf(v);
    }
    for (int e = t; e < 4096; e += 256) {
        int tile = e >> 9, lane = (e >> 3) & 63, j = e & 7;
        int m = tile >> 2, ks = tile & 3;
        int row = m * 32 + (lane & 31);
        int k = ks * 16 + (lane >> 5) * 8 + j;
        a1[e] = (unsigned short)f2bf(w1[k * 64 + row]);
    }
    for (int e = t; e < 2048; e += 256) {
        int ks = e >> 9, lane = (e >> 3) & 63, j = e & 7;
        int row = lane & 31;
        int k = ks * 16 + (lane >> 5) * 8 + j;
        float v = (row < 4) ? w2[k * 4 + row] : 0.f;
        a2[e] = (unsigned short)f2bf(v);
    }
    if (t < 64) {
        int m = t >> 5, q5 = (t >> 4) & 1, r = t & 15;
        int row = (r & 3) + 8 * (r >> 2) + 4 * q5;
        b0c[(m * 2 + q5) * 16 + r] = b0[m * 32 + row];
        b1c[(m * 2 + q5) * 16 + r] = b1[m * 32 + row];
    }
}

// ---------- grid fp32->bf16 conversion (R5-verified) ----------
__global__ void conv_grids(const float2* __restrict__ g0, const float2* __restrict__ g1,
                           const float2* __restrict__ g2, const float2* __restrict__ g3,
                           const float2* __restrict__ g4, const float2* __restrict__ g5,
                           const float2* __restrict__ g6, const float2* __restrict__ g7,
                           char* __restrict__ wsb)
{
    int b = blockIdx.x, t = threadIdx.x;
    const float2* s; unsigned* d; int cell;
    if (b < 16384)      { s = g7; d = (unsigned*)(wsb + G7_OFF); cell = b * 256 + t; }
    else if (b < 20480) { s = g6; d = (unsigned*)(wsb + G6_OFF); cell = (b - 16384) * 256 + t; }
    else if (b < 21504) { s = g5; d = (unsigned*)(wsb + G5_OFF); cell = (b - 20480) * 256 + t; }
    else if (b < 21760) { s = g4; d = (unsigned*)(wsb + G4_OFF); cell = (b - 21504) * 256 + t; }
    else if (b < 21824) { s = g3; d = (unsigned*)(wsb + G3_OFF); cell = (b - 21760) * 256 + t; }
    else if (b < 21840) { s = g2; d = (unsigned*)(wsb + G2_OFF); cell = (b - 21824) * 256 + t; }
    else if (b < 21844) { s = g1; d = (unsigned*)(wsb + G1_OFF); cell = (b - 21840) * 256 + t; }
    else                { s = g0; d = (unsigned*)(wsb + G0_OFF); cell = t; }
    float2 f = s[cell];
    d[cell] = pkbf(f.x, f.y);
}

__global__ void conv_lpe(const float4* __restrict__ src, u32x4* __restrict__ dst)
{
    int t = blockIdx.x * 256 + threadIdx.x;
    if (t < 49923) {
        float4 a = src[t * 2], b = src[t * 2 + 1];
        u32x4 o = { pkbf(a.x, a.y), pkbf(a.z, a.w), pkbf(b.x, b.y), pkbf(b.z, b.w) };
        dst[t] = o;
    }
}

// ================= shared MLP pipeline (R4/R5-verified math) =================
__device__ __forceinline__ void mlp_pair(const unsigned (&B0)[2][2][4],
                                         const float* __restrict__ ws,
                                         const float* __restrict__ b2,
                                         int lane, int q5, f32x16 (&acc2)[2])
{
    const bf16x8* A0 = (const bf16x8*)ws;
    const bf16x8* A1 = (const bf16x8*)((const char*)ws + 4096);
    const bf16x8* A2 = (const bf16x8*)((const char*)ws + 12288);
    const float4* b0c = (const float4*)((const char*)ws + 16384);
    const float4* b1c = (const float4*)((const char*)ws + 16640);

    // layer 0 (m-split) -> B1 frags
    unsigned B1[4][2][4];
#pragma unroll
    for (int m = 0; m < 2; ++m) {
        f32x16 acc[2];
#pragma unroll
        for (int cc = 0; cc < 4; ++cc) {
            float4 bq = b0c[(m * 2 + q5) * 4 + cc];
#pragma unroll
            for (int n = 0; n < 2; ++n) {
                acc[n][4 * cc + 0] = bq.x;
                acc[n][4 * cc + 1] = bq.y;
                acc[n][4 * cc + 2] = bq.z;
                acc[n][4 * cc + 3] = bq.w;
            }
        }
#pragma unroll
        for (int ks = 0; ks < 2; ++ks) {
            bf16x8 af = A0[(m * 2 + ks) * 64 + lane];
#pragma unroll
            for (int n = 0; n < 2; ++n)
                acc[n] = __builtin_amdgcn_mfma_f32_32x32x16_bf16(
                    af, mkfrag(B0[ks][n][0], B0[ks][n][1], B0[ks][n][2], B0[ks][n][3]),
                    acc[n], 0, 0, 0);
        }
#pragma unroll
        for (int t = 0; t < 2; ++t) {
#pragma unroll
            for (int n = 0; n < 2; ++n)
#pragma unroll
                for (int c = 0; c < 2; ++c) {
                    int r0 = 2 * c + 8 * t;
                    int r1 = 2 * c + 8 * t + 4;
                    unsigned P0 = pkbf(fmaxf(acc[n][r0], 0.f), fmaxf(acc[n][r0 + 1], 0.f));
                    unsigned P1 = pkbf(fmaxf(acc[n][r1], 0.f), fmaxf(acc[n][r1 + 1], 0.f));
                    auto r = __builtin_amdgcn_permlane32_swap(P1, P0, false, false);
                    B1[2 * m + t][n][c] = r[1];
                    B1[2 * m + t][n][2 + c] = r[0];
                }
        }
    }

    // layer 1 (m-split) -> B2 frags
    unsigned B2[4][2][4];
#pragma unroll
    for (int m = 0; m < 2; ++m) {
        f32x16 acc[2];
#pragma unroll
        for (int cc = 0; cc < 4; ++cc) {
            float4 bq = b1c[(m * 2 + q5) * 4 + cc];
#pragma unroll
            for (int n = 0; n < 2; ++n) {
                acc[n][4 * cc + 0] = bq.x;
                acc[n][4 * cc + 1] = bq.y;
                acc[n][4 * cc + 2] = bq.z;
                acc[n][4 * cc + 3] = bq.w;
            }
        }
#pragma unroll
        for (int ks = 0; ks < 4; ++ks) {
            bf16x8 af = A1[(m * 4 + ks) * 64 + lane];
#pragma unroll
            for (int n = 0; n < 2; ++n)
                acc[n] = __builtin_amdgcn_mfma_f32_32x32x16_bf16(
                    af, mkfrag(B1[ks][n][0], B1[ks][n][1], B1[ks][n][2], B1[ks][n][3]),
                    acc[n], 0, 0, 0);
        }
#pragma unroll
        for (int t = 0; t < 2; ++t) {
#pragma unroll
            for (int n = 0; n < 2; ++n)
#pragma unroll
                for (int c = 0; c < 2; ++c) {
                    int r0 = 2 * c + 8 * t;
                    int r1 = 2 * c + 8 * t + 4;
                    unsigned P0 = pkbf(fmaxf(acc[n][r0], 0.f), fmaxf(acc[n][r0 + 1], 0.f));
                    unsigned P1 = pkbf(fmaxf(acc[n][r1], 0.f), fmaxf(acc[n][r1 + 1], 0.f));
                    auto r = __builtin_amdgcn_permlane32_swap(P1, P0, false, false);
                    B2[2 * m + t][n][c] = r[1];
                    B2[2 * m + t][n][2 + c] = r[0];
                }
        }
    }

    // layer 2
#pragma unroll
    for (int n = 0; n < 2; ++n)
#pragma unroll
        for (int r = 0; r < 16; ++r) acc2[n][r] = (r < 4) ? b2[r] : 0.f;
#pragma unroll
    for (int ks = 0; ks < 4; ++ks) {
        bf16x8 af = A2[ks * 64 + lane];
#pragma unroll
        for (int n = 0; n < 2; ++n)
            acc2[n] = __builtin_amdgcn_mfma_f32_32x32x16_bf16(
                af, mkfrag(B2[ks][n][0], B2[ks][n][1], B2[ks][n][2], B2[ks][n][3]),
                acc2[n], 0, 0, 0);
    }
}

// ---- gather macros, suffix S distinguishes the two points per lane ----
#define GA(S, IDX, R) int b##S##IDX; float lu##S##IDX, lv##S##IDX; \
    { float fu_ = u##S * (float)((R) - 1), fv_ = v##S * (float)((R) - 1); \
      int i0_ = (int)floorf(fu_), j0_ = (int)floorf(fv_); \
      i0_ = i0_ < 0 ? 0 : (i0_ > (R) - 2 ? (R) - 2 : i0_); \
      j0_ = j0_ < 0 ? 0 : (j0_ > (R) - 2 ? (R) - 2 : j0_); \
      lu##S##IDX = fu_ - (float)i0_; lv##S##IDX = fv_ - (float)j0_; \
      b##S##IDX = i0_ + j0_ * (R); }

#define GL(S, IDX, R, OFF) \
    const unsigned* G##S##IDX = (const unsigned*)(wsb + (OFF)); \
    unsigned t##S##IDX##_0 = G##S##IDX[b##S##IDX],       t##S##IDX##_1 = G##S##IDX[b##S##IDX + 1], \
             t##S##IDX##_2 = G##S##IDX[b##S##IDX + (R)], t##S##IDX##_3 = G##S##IDX[b##S##IDX + (R) + 1];

#define GS(S, IDX) { \
    float omu_ = 1.f - lu##S##IDX, omv_ = 1.f - lv##S##IDX; \
    float w00_ = omu_ * omv_, w10_ = lu##S##IDX * omv_, w01_ = omu_ * lv##S##IDX, w11_ = lu##S##IDX * lv##S##IDX; \
    e0##S += bflo(t##S##IDX##_0) * w00_ + bflo(t##S##IDX##_1) * w10_ + bflo(t##S##IDX##_2) * w01_ + bflo(t##S##IDX##_3) * w11_; \
    e1##S += bfhi(t##S##IDX##_0) * w00_ + bfhi(t##S##IDX##_1) * w10_ + bfhi(t##S##IDX##_2) * w01_ + bfhi(t##S##IDX##_3) * w11_; }

#define LPEA(S) float lu_pe##S, lv_pe##S; int lc##S; \
    { float fu = u##S * 128.f, fv = v##S * 128.f; \
      int i0 = (int)floorf(fu), j0 = (int)floorf(fv); \
      i0 = i0 < 0 ? 0 : (i0 > 127 ? 127 : i0); \
      j0 = j0 < 0 ? 0 : (j0 > 127 ? 127 : j0); \
      lu_pe##S = fu - (float)i0; lv_pe##S = fv - (float)j0; \
      lc##S = (i0 + j0 * 129) * 3; }

#define LPEL(S) \
    u32x4 L##S##00a = LP[lc##S],       L##S##00b = LP[lc##S + 1],   L##S##00c = LP[lc##S + 2], \
          L##S##10a = LP[lc##S + 3],   L##S##10b = LP[lc##S + 4],   L##S##10c = LP[lc##S + 5], \
          L##S##01a = LP[lc##S + 387], L##S##01b = LP[lc##S + 388], L##S##01c = LP[lc##S + 389], \
          L##S##11a = LP[lc##S + 390], L##S##11b = LP[lc##S + 391], L##S##11c = LP[lc##S + 392];

#define LPW(S, W, A, B, C, Dd) \
    coeff##S[2*(W)]   = bflo(A)*q00 + bflo(B)*q10 + bflo(C)*q01 + bflo(Dd)*q11; \
    coeff##S[2*(W)+1] = bfhi(A)*q00 + bfhi(B)*q10 + bfhi(C)*q01 + bfhi(Dd)*q11;

#define LPEC(S) { \
    float omu = 1.f - lu_pe##S, omv = 1.f - lv_pe##S; \
    float q00 = omu * omv, q10 = lu_pe##S * omv, q01 = omu * lv_pe##S, q11 = lu_pe##S * lv_pe##S; \
    LPW(S, 0,  L##S##00a[0], L##S##10a[0], L##S##01a[0], L##S##11a[0]) \
    LPW(S, 1,  L##S##00a[1], L##S##10a[1], L##S##01a[1], L##S##11a[1]) \
    LPW(S, 2,  L##S##00a[2], L##S##10a[2], L##S##01a[2], L##S##11a[2]) \
    LPW(S, 3,  L##S##00a[3], L##S##10a[3], L##S##01a[3], L##S##11a[3]) \
    LPW(S, 4,  L##S##00b[0], L##S##10b[0], L##S##01b[0], L##S##11b[0]) \
    LPW(S, 5,  L##S##00b[1], L##S##10b[1], L##S##01b[1], L##S##11b[1]) \
    LPW(S, 6,  L##S##00b[2], L##S##10b[2], L##S##01b[2], L##S##11b[2]) \
    LPW(S, 7,  L##S##00b[3], L##S##10b[3], L##S##01b[3], L##S##11b[3]) \
    LPW(S, 8,  L##S##00c[0], L##S##10c[0], L##S##01c[0], L##S##11c[0]) \
    LPW(S, 9,  L##S##00c[1], L##S##10c[1], L##S##01c[1], L##S##11c[1]) \
    LPW(S, 10, L##S##00c[2], L##S##10c[2], L##S##01c[2], L##S##11c[2]) \
    LPW(S, 11, L##S##00c[3], L##S##10c[3], L##S##01c[3], L##S##11c[3]) }

#define TRIG(S) float pe##S[16]; \
    _Pragma("unroll") \
    for (int kf = 0; kf < NF; ++kf) { \
        const float fr = 6.28318530717958647692f * (float)(1 << kf); \
        float au = lu_pe##S * fr; \
        float av = lv_pe##S * fr; \
        pe##S[kf]          = __cosf(au); \
        pe##S[NF + kf]     = __sinf(au); \
        pe##S[2 * NF + kf] = __cosf(av); \
        pe##S[3 * NF + kf] = __sinf(av); }

#define FEATPACK(S) unsigned fd##S[16]; { \
    float feat[32]; \
    feat[0] = e0##S; feat[1] = e1##S; \
    _Pragma("unroll") \
    for (int q = 0; q < D0; ++q) feat[2 + q] = coeff##S[q]; \
    _Pragma("unroll") \
    for (int q = 0; q < 4 * NF; ++q) feat[2 + D0 + q] = coeff##S[D0 + q] * pe##S[q]; \
    _Pragma("unroll") \
    for (int q = 26; q < 32; ++q) feat[q] = 0.f; \
    _Pragma("unroll") \
    for (int i = 0; i < 16; ++i) fd##S[i] = pkbf(feat[2 * i], feat[2 * i + 1]); }

#define B0BUILD(S, DST) unsigned DST[2][2][4]; \
    _Pragma("unroll") \
    for (int ks = 0; ks < 2; ++ks) \
    _Pragma("unroll") \
        for (int j2 = 0; j2 < 4; ++j2) { \
            unsigned a_ = fd##S[8 * ks + j2]; \
            unsigned b_ = fd##S[8 * ks + 4 + j2]; \
            auto r_ = __builtin_amdgcn_permlane32_swap(b_, a_, false, false); \
            DST[ks][1][j2] = r_[0]; \
            DST[ks][0][j2] = r_[1]; }

// ---------- main fused kernel: 2 points per lane, deep load batch ----------
__global__ __launch_bounds__(256, 4)
void colornet_mfma2(const float* __restrict__ coords,
                    const float* __restrict__ ws,
                    const float* __restrict__ b2,
                    f32x4* __restrict__ out)
{
    const int lane = threadIdx.x & 63;
    const int wave = threadIdx.x >> 6;
    const int q5 = lane >> 5;
    const int base_pt = blockIdx.x * 512 + wave * 128;
    const char* wsb = (const char*)ws;
    const u32x4* LP = (const u32x4*)(wsb + LPE_OFF);

    // coords for both points
    const float* cpA = coords + 2 * (base_pt + lane);
    const float* cpB = coords + 2 * (base_pt + 64 + lane);
    float cxA = __builtin_nontemporal_load(cpA);
    float cyA = __builtin_nontemporal_load(cpA + 1);
    float cxB = __builtin_nontemporal_load(cpB);
    float cyB = __builtin_nontemporal_load(cpB + 1);
    float uA = fminf(fmaxf(cxA, 0.f), 1.f - 1e-6f);
    float vA = fminf(fmaxf(cyA, 0.f), 1.f - 1e-6f);
    float uB = fminf(fmaxf(cxB, 0.f), 1.f - 1e-6f);
    float vB = fminf(fmaxf(cyB, 0.f), 1.f - 1e-6f);

    float e0A = 0.f, e1A = 0.f, e0B = 0.f, e1B = 0.f;
    float coeffA[LPE_OUT], coeffB[LPE_OUT];

    // ---- addresses for all grid levels, both points ----
    GA(A, 7, 2048) GA(A, 6, 1024) GA(A, 5, 512) GA(A, 4, 256)
    GA(A, 3, 128)  GA(A, 2, 64)   GA(A, 1, 32)  GA(A, 0, 16)
    GA(B, 7, 2048) GA(B, 6, 1024) GA(B, 5, 512) GA(B, 4, 256)
    GA(B, 3, 128)  GA(B, 2, 64)   GA(B, 1, 32)  GA(B, 0, 16)

    // ---- issue both points' grid loads back-to-back (64 dwords in flight) ----
    GL(A, 7, 2048, G7_OFF) GL(B, 7, 2048, G7_OFF)
    GL(A, 6, 1024, G6_OFF) GL(B, 6, 1024, G6_OFF)
    GL(A, 5, 512,  G5_OFF) GL(B, 5, 512,  G5_OFF)
    GL(A, 4, 256,  G4_OFF) GL(B, 4, 256,  G4_OFF)
    GL(A, 3, 128,  G3_OFF) GL(B, 3, 128,  G3_OFF)
    GL(A, 2, 64,   G2_OFF) GL(B, 2, 64,   G2_OFF)
    GL(A, 1, 32,   G1_OFF) GL(B, 1, 32,   G1_OFF)
    GL(A, 0, 16,   G0_OFF) GL(B, 0, 16,   G0_OFF)

    // ---- LPE A issue; trig for both under the flight window ----
    LPEA(A) LPEA(B)
    LPEL(A)
    TRIG(A) TRIG(B)

    // ---- consume grid A, issue LPE B, consume grid B ----
    GS(A, 7) GS(A, 6) GS(A, 5) GS(A, 4) GS(A, 3) GS(A, 2) GS(A, 1) GS(A, 0)
    LPEL(B)
    GS(B, 7) GS(B, 6) GS(B, 5) GS(B, 4) GS(B, 3) GS(B, 2) GS(B, 1) GS(B, 0)

    // ---- consume LPE ----
    LPEC(A)
    LPEC(B)

    // ---- features -> bf16 -> B0 fragments ----
    FEATPACK(A)
    FEATPACK(B)
    B0BUILD(A, B0a)
    B0BUILD(B, B0b)

    // ---- MLP pair 0 (points base..base+63) ----
    {
        f32x16 acc2[2];
        mlp_pair(B0a, ws, b2, lane, q5, acc2);
        if (lane < 32) {
#pragma unroll
            for (int n = 0; n < 2; ++n) {
                f32x4 o;
                o[0] = 1.f / (1.f + __expf(-acc2[n][0]));
                o[1] = 1.f / (1.f + __expf(-acc2[n][1]));
                o[2] = 1.f / (1.f + __expf(-acc2[n][2]));
                o[3] = 1.f / (1.f + __expf(-acc2[n][3]));
                __builtin_nontemporal_store(o, out + (base_pt + 32 * n + lane));
            }
        }
    }
    // ---- MLP pair 1 (points base+64..base+127) ----
    {
        f32x16 acc2[2];
        mlp_pair(B0b, ws, b2, lane, q5, acc2);
        if (lane < 32) {
#pragma unroll
            for (int n = 0; n < 2; ++n) {
                f32x4 o;
                o[0] = 1.f / (1.f + __expf(-acc2[n][0]));
                o[1] = 1.f / (1.f + __expf(-acc2[n][1]));
                o[2] = 1.f / (1.f + __expf(-acc2[n][2]));
                o[3] = 1.f / (1.f + __expf(-acc2[n][3]));
                __builtin_nontemporal_store(o, out + (base_pt + 64 + 32 * n + lane));
            }
        }
    }
}

// ---------- fp32 single-point fallback (R4-verified; used only if ws too small) ----------
template<int R>
__device__ __forceinline__ void gather_level(const float* __restrict__ g,
                                             float u, float v,
                                             float& e0, float& e1) {
    const float scale = (float)(R - 1);
    float fu = u * scale, fv = v * scale;
    int i0 = (int)floorf(fu);
    int j0 = (int)floorf(fv);
    i0 = i0 < 0 ? 0 : (i0 > R - 2 ? R - 2 : i0);
    j0 = j0 < 0 ? 0 : (j0 > R - 2 ? R - 2 : j0);
    float lu = fu - (float)i0;
    float lv = fv - (float)j0;
    const float2* gg = (const float2*)g;
    int base = i0 + j0 * R;
    float2 f00 = gg[base];
    float2 f10 = gg[base + 1];
    float2 f01 = gg[base + R];
    float2 f11 = gg[base + R + 1];
    float omu = 1.f - lu, omv = 1.f - lv;
    float w00 = omu * omv, w10 = lu * omv, w01 = omu * lv, w11 = lu * lv;
    e0 += f00.x * w00 + f10.x * w10 + f01.x * w01 + f11.x * w11;
    e1 += f00.y * w00 + f10.y * w10 + f01.y * w01 + f11.y * w11;
}

__global__ __launch_bounds__(256, 4)
void colornet_fp32(const float* __restrict__ coords,
                   const float* __restrict__ g0, const float* __restrict__ g1,
                   const float* __restrict__ g2, const float* __restrict__ g3,
                   const float* __restrict__ g4, const float* __restrict__ g5,
                   const float* __restrict__ g6, const float* __restrict__ g7,
                   const float* __restrict__ lpe,
                   const float* __restrict__ ws,
                   const float* __restrict__ b2,
                   f32x4* __restrict__ out)
{
    const int lane = threadIdx.x & 63;
    const int wave = threadIdx.x >> 6;
    const int q5 = lane >> 5;
    const int base_pt = blockIdx.x * 256 + wave * 64;
    const int point = base_pt + lane;

    const float* cp = coords + 2 * point;
    float cx = __builtin_nontemporal_load(cp);
    float cy = __builtin_nontemporal_load(cp + 1);
    float uA = fminf(fmaxf(cx, 0.f), 1.f - 1e-6f);
    float vA = fminf(fmaxf(cy, 0.f), 1.f - 1e-6f);

    float e0 = 0.f, e1 = 0.f;
    gather_level<16>(g0, uA, vA, e0, e1);
    gather_level<32>(g1, uA, vA, e0, e1);
    gather_level<64>(g2, uA, vA, e0, e1);
    gather_level<128>(g3, uA, vA, e0, e1);
    gather_level<256>(g4, uA, vA, e0, e1);
    gather_level<512>(g5, uA, vA, e0, e1);
    gather_level<1024>(g6, uA, vA, e0, e1);
    gather_level<2048>(g7, uA, vA, e0, e1);

    float coeff[LPE_OUT];
    float lu_pe, lv_pe;
    {
        float fu = uA * 128.f, fv = vA * 128.f;
        int i0 = (int)floorf(fu);
        int j0 = (int)floorf(fv);
        i0 = i0 < 0 ? 0 : (i0 > 127 ? 127 : i0);
        j0 = j0 < 0 ? 0 : (j0 > 127 ? 127 : j0);
        lu_pe = fu - (float)i0;
        lv_pe = fv - (float)j0;
        int base = (i0 + j0 * 129) * LPE_OUT;
        const float4* p00 = (const float4*)(lpe + base);
        const float4* p10 = (const float4*)(lpe + base + LPE_OUT);
        const float4* p01 = (const float4*)(lpe + base + 129 * LPE_OUT);
        const float4* p11 = (const float4*)(lpe + base + 130 * LPE_OUT);
        float omu = 1.f - lu_pe, omv = 1.f - lv_pe;
        float w00 = omu * omv, w10 = lu_pe * omv, w01 = omu * lv_pe, w11 = lu_pe * lv_pe;
#pragma unroll
        for (int q = 0; q < 6; ++q) {
            float4 a = p00[q], bq = p10[q], cq = p01[q], dq = p11[q];
            coeff[4 * q + 0] = a.x * w00 + bq.x * w10 + cq.x * w01 + dq.x * w11;
            coeff[4 * q + 1] = a.y * w00 + bq.y * w10 + cq.y * w01 + dq.y * w11;
            coeff[4 * q + 2] = a.z * w00 + bq.z * w10 + cq.z * w01 + dq.z * w11;
            coeff[4 * q + 3] = a.w * w00 + bq.w * w10 + cq.w * w01 + dq.w * w11;
        }
    }

    float pe[16];
#pragma unroll
    for (int kf = 0; kf < NF; ++kf) {
        const float fr = 6.28318530717958647692f * (float)(1 << kf);
        float au = lu_pe * fr;
        float av = lv_pe * fr;
        pe[kf]          = __cosf(au);
        pe[NF + kf]     = __sinf(au);
        pe[2 * NF + kf] = __cosf(av);
        pe[3 * NF + kf] = __sinf(av);
    }

    float feat[32];
    feat[0] = e0; feat[1] = e1;
#pragma unroll
    for (int q = 0; q < D0; ++q) feat[2 + q] = coeff[q];
#pragma unroll
    for (int q = 0; q < 4 * NF; ++q) feat[2 + D0 + q] = coeff[D0 + q] * pe[q];
#pragma unroll
    for (int q = 26; q < 32; ++q) feat[q] = 0.f;

    unsigned fd[16];
#pragma unroll
    for (int i = 0; i < 16; ++i) fd[i] = pkbf(feat[2 * i], feat[2 * i + 1]);

    unsigned B0[2][2][4];
#pragma unroll
    for (int ks = 0; ks < 2; ++ks)
#pragma unroll
        for (int j2 = 0; j2 < 4; ++j2) {
            unsigned a = fd[8 * ks + j2];
            unsigned b = fd[8 * ks + 4 + j2];
            auto r = __builtin_amdgcn_permlane32_swap(b, a, false, false);
            B0[ks][1][j2] = r[0];
            B0[ks][0][j2] = r[1];
        }

    f32x16 acc2[2];
    mlp_pair(B0, ws, b2, lane, q5, acc2);
    if (lane < 32) {
#pragma unroll
        for (int n = 0; n < 2; ++n) {
            f32x4 o;
            o[0] = 1.f / (1.f + __expf(-acc2[n][0]));
            o[1] = 1.f / (1.f + __expf(-acc2[n][1]));
            o[2] = 1.f / (1.f + __expf(-acc2[n][2]));
            o[3] = 1.f / (1.f + __expf(-acc2[n][3]));
            __builtin_nontemporal_store(o, out + (base_pt + 32 * n + lane));
        }
    }
}

extern "C" void kernel_launch(void* const* d_in, const int* in_sizes, int n_in,
                              void* d_out, int out_size, void* d_ws, size_t ws_size,
                              hipStream_t stream) {
    const float* coords = (const float*)d_in[0];
    const float* g0 = (const float*)d_in[1];
    const float* g1 = (const float*)d_in[2];
    const float* g2 = (const float*)d_in[3];
    const float* g3 = (const float*)d_in[4];
    const float* g4 = (const float*)d_in[5];
    const float* g5 = (const float*)d_in[6];
    const float* g6 = (const float*)d_in[7];
    const float* g7 = (const float*)d_in[8];
    const float* lpe = (const float*)d_in[9];
    const float* w0 = (const float*)d_in[10];
    const float* b0 = (const float*)d_in[11];
    const float* w1 = (const float*)d_in[12];
    const float* b1 = (const float*)d_in[13];
    const float* w2 = (const float*)d_in[14];
    const float* b2 = (const float*)d_in[15];
    f32x4* out = (f32x4*)d_out;

    int B = in_sizes[0] / 2;

    prep_kernel<<<1, 256, 0, stream>>>(w0, b0, w1, b1, w2, (float*)d_ws);

    if (ws_size >= WS_NEED) {
        conv_grids<<<21845, 256, 0, stream>>>((const float2*)g0, (const float2*)g1,
                                              (const float2*)g2, (const float2*)g3,
                                              (const float2*)g4, (const float2*)g5,
                                              (const float2*)g6, (const float2*)g7,
                                              (char*)d_ws);
        conv_lpe<<<196, 256, 0, stream>>>((const float4*)lpe,
                                          (u32x4*)((char*)d_ws + LPE_OFF));
        colornet_mfma2<<<B / 512, 256, 0, stream>>>(coords, (const float*)d_ws, b2, out);
    } else {
        colornet_fp32<<<B / 256, 256, 0, stream>>>(coords, g0, g1, g2, g3, g4, g5, g6, g7,
                                                   lpe, (const float*)d_ws, b2, out);
    }
}

// Round 7
// 146.423 us; speedup vs baseline: 2.6512x; 2.6512x over previous
//
#include <hip/hip_runtime.h>
#include <math.h>

typedef short bf16x8 __attribute__((ext_vector_type(8)));
typedef float f32x16 __attribute__((ext_vector_type(16)));
typedef float f32x4 __attribute__((ext_vector_type(4)));
typedef unsigned u32x4 __attribute__((ext_vector_type(4)));

#define NF 4
#define D0 8
#define LPE_OUT 24

// ---------------- ws byte layout ----------------
#define LPE_OFF   17408
#define G0_OFF    816384
#define G1_OFF    817408
#define G2_OFF    821504
#define G3_OFF    837888
#define G4_OFF    903424
#define G5_OFF    1165568
#define G6_OFF    2214144
#define G7_OFF    6408448
#define WS_NEED   23185664ULL
// sort region (only used when ws_size >= WS_NEED2 and B == 1<<20)
#define PART_OFF   23187456ULL               // 4096 blocks x 256 buckets u32 = 4 MB
#define STARTS_OFF 27381760ULL               // totals[256] + starts[256]
#define SCOORD_OFF 27385856ULL               // sorted float2 coords, 8 MB
#define PERM_OFF   35774464ULL               // u32 perm, 4 MB
#define WS_NEED2   39968768ULL

// ---------- bf16 helpers ----------
__device__ __forceinline__ unsigned f2bf(float x) {
    unsigned u = __float_as_uint(x);
    u = u + 0x7fffu + ((u >> 16) & 1u);
    return u >> 16;
}
__device__ __forceinline__ unsigned pkbf(float a, float b) {
    return f2bf(a) | (f2bf(b) << 16);
}
__device__ __forceinline__ float bflo(unsigned u) { return __uint_as_float(u << 16); }
__device__ __forceinline__ float bfhi(unsigned u) { return __uint_as_float(u & 0xffff0000u); }
__device__ __forceinline__ bf16x8 mkfrag(unsigned w0, unsigned w1, unsigned w2, unsigned w3) {
    u32x4 u = { w0, w1, w2, w3 };
    return __builtin_bit_cast(bf16x8, u);
}

// ---------- weight prep (R3/R4-verified, unchanged) ----------
__global__ void prep_kernel(const float* __restrict__ w0, const float* __restrict__ b0,
                            const float* __restrict__ w1, const float* __restrict__ b1,
                            const float* __restrict__ w2, float* __restrict__ ws)
{
    int t = threadIdx.x;
    unsigned short* a0 = (unsigned short*)ws;
    unsigned short* a1 = a0 + 2048;
    unsigned short* a2 = a1 + 4096;
    float* b0c = (float*)(a2 + 2048);
    float* b1c = b0c + 64;

    for (int e = t; e < 2048; e += 256) {
        int tile = e >> 9, lane = (e >> 3) & 63, j = e & 7;
        int m = tile >> 1, ks = tile & 1;
        int row = m * 32 + (lane & 31);
        int k = ks * 16 + (lane >> 5) * 8 + j;
        float v = (k < 26) ? w0[k * 64 + row] : 0.f;
        a0[e] = (unsigned short)f2bf(v);
    }
    for (int e = t; e < 4096; e += 256) {
        int tile = e >> 9, lane = (e >> 3) & 63, j = e & 7;
        int m = tile >> 2, ks = tile & 3;
        int row = m * 32 + (lane & 31);
        int k = ks * 16 + (lane >> 5) * 8 + j;
        a1[e] = (unsigned short)f2bf(w1[k * 64 + row]);
    }
    for (int e = t; e < 2048; e += 256) {
        int ks = e >> 9, lane = (e >> 3) & 63, j = e & 7;
        int row = lane & 31;
        int k = ks * 16 + (lane >> 5) * 8 + j;
        float v = (row < 4) ? w2[k * 4 + row] : 0.f;
        a2[e] = (unsigned short)f2bf(v);
    }
    if (t < 64) {
        int m = t >> 5, q5 = (t >> 4) & 1, r = t & 15;
        int row = (r & 3) + 8 * (r >> 2) + 4 * q5;
        b0c[(m * 2 + q5) * 16 + r] = b0[m * 32 + row];
        b1c[(m * 2 + q5) * 16 + r] = b1[m * 32 + row];
    }
}

// ---------- grid fp32->bf16 conversion (R5-verified) ----------
__global__ void conv_grids(const float2* __restrict__ g0, const float2* __restrict__ g1,
                           const float2* __restrict__ g2, const float2* __restrict__ g3,
                           const float2* __restrict__ g4, const float2* __restrict__ g5,
                           const float2* __restrict__ g6, const float2* __restrict__ g7,
                           char* __restrict__ wsb)
{
    int b = blockIdx.x, t = threadIdx.x;
    const float2* s; unsigned* d; int cell;
    if (b < 16384)      { s = g7; d = (unsigned*)(wsb + G7_OFF); cell = b * 256 + t; }
    else if (b < 20480) { s = g6; d = (unsigned*)(wsb + G6_OFF); cell = (b - 16384) * 256 + t; }
    else if (b < 21504) { s = g5; d = (unsigned*)(wsb + G5_OFF); cell = (b - 20480) * 256 + t; }
    else if (b < 21760) { s = g4; d = (unsigned*)(wsb + G4_OFF); cell = (b - 21504) * 256 + t; }
    else if (b < 21824) { s = g3; d = (unsigned*)(wsb + G3_OFF); cell = (b - 21760) * 256 + t; }
    else if (b < 21840) { s = g2; d = (unsigned*)(wsb + G2_OFF); cell = (b - 21824) * 256 + t; }
    else if (b < 21844) { s = g1; d = (unsigned*)(wsb + G1_OFF); cell = (b - 21840) * 256 + t; }
    else                { s = g0; d = (unsigned*)(wsb + G0_OFF); cell = t; }
    float2 f = s[cell];
    d[cell] = pkbf(f.x, f.y);
}

__global__ void conv_lpe(const float4* __restrict__ src, u32x4* __restrict__ dst)
{
    int t = blockIdx.x * 256 + threadIdx.x;
    if (t < 49923) {
        float4 a = src[t * 2], b = src[t * 2 + 1];
        u32x4 o = { pkbf(a.x, a.y), pkbf(a.z, a.w), pkbf(b.x, b.y), pkbf(b.z, b.w) };
        dst[t] = o;
    }
}

// ================= counting sort into 256 uv-buckets =================
__device__ __forceinline__ int bucket_of(float cx, float cy) {
    float u = fminf(fmaxf(cx, 0.f), 1.f - 1e-6f);
    float v = fminf(fmaxf(cy, 0.f), 1.f - 1e-6f);
    return (int)(v * 16.f) * 16 + (int)(u * 16.f);
}

__global__ __launch_bounds__(256)
void sort_hist(const float2* __restrict__ coords, unsigned* __restrict__ part)
{
    __shared__ unsigned h[256];
    int t = threadIdx.x;
    h[t] = 0;
    __syncthreads();
    float2 c = coords[blockIdx.x * 256 + t];
    atomicAdd(&h[bucket_of(c.x, c.y)], 1u);
    __syncthreads();
    part[blockIdx.x * 256 + t] = h[t];     // part[j*256 + bucket]
}

__global__ __launch_bounds__(256)
void sort_totals(const unsigned* __restrict__ part, unsigned* __restrict__ totals)
{
    int bucket = blockIdx.x, t = threadIdx.x;
    unsigned s = 0;
    for (int j = t; j < 4096; j += 256) s += part[j * 256 + bucket];
    __shared__ unsigned red[256];
    red[t] = s;
    __syncthreads();
    for (int off = 128; off > 0; off >>= 1) {
        if (t < off) red[t] += red[t + off];
        __syncthreads();
    }
    if (t == 0) totals[bucket] = red[0];
}

__global__ __launch_bounds__(256)
void sort_starts(const unsigned* __restrict__ totals, unsigned* __restrict__ starts)
{
    int t = threadIdx.x;
    __shared__ unsigned s[256];
    unsigned mine = totals[t];
    s[t] = mine;
    __syncthreads();
    for (int off = 1; off < 256; off <<= 1) {
        unsigned v = (t >= off) ? s[t - off] : 0u;
        __syncthreads();
        s[t] += v;
        __syncthreads();
    }
    starts[t] = s[t] - mine;   // exclusive
}

__global__ __launch_bounds__(256)
void sort_offsets(unsigned* __restrict__ part, const unsigned* __restrict__ starts)
{
    int bucket = blockIdx.x, t = threadIdx.x;
    unsigned loc[16];
    unsigned s = 0;
#pragma unroll
    for (int k = 0; k < 16; ++k) {
        loc[k] = part[(16 * t + k) * 256 + bucket];
        s += loc[k];
    }
    __shared__ unsigned sc[256];
    sc[t] = s;
    __syncthreads();
    for (int off = 1; off < 256; off <<= 1) {
        unsigned v = (t >= off) ? sc[t - off] : 0u;
        __syncthreads();
        sc[t] += v;
        __syncthreads();
    }
    unsigned base = starts[bucket] + sc[t] - s;
#pragma unroll
    for (int k = 0; k < 16; ++k) {
        unsigned tmp = loc[k];
        part[(16 * t + k) * 256 + bucket] = base;   // in-place -> offsets
        base += tmp;
    }
}

__global__ __launch_bounds__(256)
void sort_scatter(const float2* __restrict__ coords, const unsigned* __restrict__ offs,
                  float2* __restrict__ scoord, unsigned* __restrict__ perm)
{
    __shared__ unsigned cnt[256];
    __shared__ unsigned base[256];
    int t = threadIdx.x;
    cnt[t] = 0;
    base[t] = offs[blockIdx.x * 256 + t];
    __syncthreads();
    int i = blockIdx.x * 256 + t;
    float2 c = coords[i];
    int b = bucket_of(c.x, c.y);
    unsigned r = atomicAdd(&cnt[b], 1u);
    unsigned slot = base[b] + r;
    scoord[slot] = c;
    perm[slot] = (unsigned)i;
}

// ================= shared MLP pipeline (R4/R5/R6-verified math) =================
__device__ __forceinline__ void mlp_pair(const unsigned (&B0)[2][2][4],
                                         const float* __restrict__ ws,
                                         const float* __restrict__ b2,
                                         int lane, int q5, f32x16 (&acc2)[2])
{
    const bf16x8* A0 = (const bf16x8*)ws;
    const bf16x8* A1 = (const bf16x8*)((const char*)ws + 4096);
    const bf16x8* A2 = (const bf16x8*)((const char*)ws + 12288);
    const float4* b0c = (const float4*)((const char*)ws + 16384);
    const float4* b1c = (const float4*)((const char*)ws + 16640);

    unsigned B1[4][2][4];
#pragma unroll
    for (int m = 0; m < 2; ++m) {
        f32x16 acc[2];
#pragma unroll
        for (int cc = 0; cc < 4; ++cc) {
            float4 bq = b0c[(m * 2 + q5) * 4 + cc];
#pragma unroll
            for (int n = 0; n < 2; ++n) {
                acc[n][4 * cc + 0] = bq.x;
                acc[n][4 * cc + 1] = bq.y;
                acc[n][4 * cc + 2] = bq.z;
                acc[n][4 * cc + 3] = bq.w;
            }
        }
#pragma unroll
        for (int ks = 0; ks < 2; ++ks) {
            bf16x8 af = A0[(m * 2 + ks) * 64 + lane];
#pragma unroll
            for (int n = 0; n < 2; ++n)
                acc[n] = __builtin_amdgcn_mfma_f32_32x32x16_bf16(
                    af, mkfrag(B0[ks][n][0], B0[ks][n][1], B0[ks][n][2], B0[ks][n][3]),
                    acc[n], 0, 0, 0);
        }
#pragma unroll
        for (int t = 0; t < 2; ++t) {
#pragma unroll
            for (int n = 0; n < 2; ++n)
#pragma unroll
                for (int c = 0; c < 2; ++c) {
                    int r0 = 2 * c + 8 * t;
                    int r1 = 2 * c + 8 * t + 4;
                    unsigned P0 = pkbf(fmaxf(acc[n][r0], 0.f), fmaxf(acc[n][r0 + 1], 0.f));
                    unsigned P1 = pkbf(fmaxf(acc[n][r1], 0.f), fmaxf(acc[n][r1 + 1], 0.f));
                    auto r = __builtin_amdgcn_permlane32_swap(P1, P0, false, false);
                    B1[2 * m + t][n][c] = r[1];
                    B1[2 * m + t][n][2 + c] = r[0];
                }
        }
    }

    unsigned B2[4][2][4];
#pragma unroll
    for (int m = 0; m < 2; ++m) {
        f32x16 acc[2];
#pragma unroll
        for (int cc = 0; cc < 4; ++cc) {
            float4 bq = b1c[(m * 2 + q5) * 4 + cc];
#pragma unroll
            for (int n = 0; n < 2; ++n) {
                acc[n][4 * cc + 0] = bq.x;
                acc[n][4 * cc + 1] = bq.y;
                acc[n][4 * cc + 2] = bq.z;
                acc[n][4 * cc + 3] = bq.w;
            }
        }
#pragma unroll
        for (int ks = 0; ks < 4; ++ks) {
            bf16x8 af = A1[(m * 4 + ks) * 64 + lane];
#pragma unroll
            for (int n = 0; n < 2; ++n)
                acc[n] = __builtin_amdgcn_mfma_f32_32x32x16_bf16(
                    af, mkfrag(B1[ks][n][0], B1[ks][n][1], B1[ks][n][2], B1[ks][n][3]),
                    acc[n], 0, 0, 0);
        }
#pragma unroll
        for (int t = 0; t < 2; ++t) {
#pragma unroll
            for (int n = 0; n < 2; ++n)
#pragma unroll
                for (int c = 0; c < 2; ++c) {
                    int r0 = 2 * c + 8 * t;
                    int r1 = 2 * c + 8 * t + 4;
                    unsigned P0 = pkbf(fmaxf(acc[n][r0], 0.f), fmaxf(acc[n][r0 + 1], 0.f));
                    unsigned P1 = pkbf(fmaxf(acc[n][r1], 0.f), fmaxf(acc[n][r1 + 1], 0.f));
                    auto r = __builtin_amdgcn_permlane32_swap(P1, P0, false, false);
                    B2[2 * m + t][n][c] = r[1];
                    B2[2 * m + t][n][2 + c] = r[0];
                }
        }
    }

#pragma unroll
    for (int n = 0; n < 2; ++n)
#pragma unroll
        for (int r = 0; r < 16; ++r) acc2[n][r] = (r < 4) ? b2[r] : 0.f;
#pragma unroll
    for (int ks = 0; ks < 4; ++ks) {
        bf16x8 af = A2[ks * 64 + lane];
#pragma unroll
        for (int n = 0; n < 2; ++n)
            acc2[n] = __builtin_amdgcn_mfma_f32_32x32x16_bf16(
                af, mkfrag(B2[ks][n][0], B2[ks][n][1], B2[ks][n][2], B2[ks][n][3]),
                acc2[n], 0, 0, 0);
    }
}

// ---- gather macros (R6-verified) ----
#define GA(S, IDX, R) int b##S##IDX; float lu##S##IDX, lv##S##IDX; \
    { float fu_ = u##S * (float)((R) - 1), fv_ = v##S * (float)((R) - 1); \
      int i0_ = (int)floorf(fu_), j0_ = (int)floorf(fv_); \
      i0_ = i0_ < 0 ? 0 : (i0_ > (R) - 2 ? (R) - 2 : i0_); \
      j0_ = j0_ < 0 ? 0 : (j0_ > (R) - 2 ? (R) - 2 : j0_); \
      lu##S##IDX = fu_ - (float)i0_; lv##S##IDX = fv_ - (float)j0_; \
      b##S##IDX = i0_ + j0_ * (R); }

#define GL(S, IDX, R, OFF) \
    const unsigned* G##S##IDX = (const unsigned*)(wsb + (OFF)); \
    unsigned t##S##IDX##_0 = G##S##IDX[b##S##IDX],       t##S##IDX##_1 = G##S##IDX[b##S##IDX + 1], \
             t##S##IDX##_2 = G##S##IDX[b##S##IDX + (R)], t##S##IDX##_3 = G##S##IDX[b##S##IDX + (R) + 1];

#define GS(S, IDX) { \
    float omu_ = 1.f - lu##S##IDX, omv_ = 1.f - lv##S##IDX; \
    float w00_ = omu_ * omv_, w10_ = lu##S##IDX * omv_, w01_ = omu_ * lv##S##IDX, w11_ = lu##S##IDX * lv##S##IDX; \
    e0##S += bflo(t##S##IDX##_0) * w00_ + bflo(t##S##IDX##_1) * w10_ + bflo(t##S##IDX##_2) * w01_ + bflo(t##S##IDX##_3) * w11_; \
    e1##S += bfhi(t##S##IDX##_0) * w00_ + bfhi(t##S##IDX##_1) * w10_ + bfhi(t##S##IDX##_2) * w01_ + bfhi(t##S##IDX##_3) * w11_; }

#define LPEA(S) float lu_pe##S, lv_pe##S; int lc##S; \
    { float fu = u##S * 128.f, fv = v##S * 128.f; \
      int i0 = (int)floorf(fu), j0 = (int)floorf(fv); \
      i0 = i0 < 0 ? 0 : (i0 > 127 ? 127 : i0); \
      j0 = j0 < 0 ? 0 : (j0 > 127 ? 127 : j0); \
      lu_pe##S = fu - (float)i0; lv_pe##S = fv - (float)j0; \
      lc##S = (i0 + j0 * 129) * 3; }

#define LPEL(S) \
    u32x4 L##S##00a = LP[lc##S],       L##S##00b = LP[lc##S + 1],   L##S##00c = LP[lc##S + 2], \
          L##S##10a = LP[lc##S + 3],   L##S##10b = LP[lc##S + 4],   L##S##10c = LP[lc##S + 5], \
          L##S##01a = LP[lc##S + 387], L##S##01b = LP[lc##S + 388], L##S##01c = LP[lc##S + 389], \
          L##S##11a = LP[lc##S + 390], L##S##11b = LP[lc##S + 391], L##S##11c = LP[lc##S + 392];

#define LPW(S, W, A, B, C, Dd) \
    coeff##S[2*(W)]   = bflo(A)*q00 + bflo(B)*q10 + bflo(C)*q01 + bflo(Dd)*q11; \
    coeff##S[2*(W)+1] = bfhi(A)*q00 + bfhi(B)*q10 + bfhi(C)*q01 + bfhi(Dd)*q11;

#define LPEC(S) { \
    float omu = 1.f - lu_pe##S, omv = 1.f - lv_pe##S; \
    float q00 = omu * omv, q10 = lu_pe##S * omv, q01 = omu * lv_pe##S, q11 = lu_pe##S * lv_pe##S; \
    LPW(S, 0,  L##S##00a[0], L##S##10a[0], L##S##01a[0], L##S##11a[0]) \
    LPW(S, 1,  L##S##00a[1], L##S##10a[1], L##S##01a[1], L##S##11a[1]) \
    LPW(S, 2,  L##S##00a[2], L##S##10a[2], L##S##01a[2], L##S##11a[2]) \
    LPW(S, 3,  L##S##00a[3], L##S##10a[3], L##S##01a[3], L##S##11a[3]) \
    LPW(S, 4,  L##S##00b[0], L##S##10b[0], L##S##01b[0], L##S##11b[0]) \
    LPW(S, 5,  L##S##00b[1], L##S##10b[1], L##S##01b[1], L##S##11b[1]) \
    LPW(S, 6,  L##S##00b[2], L##S##10b[2], L##S##01b[2], L##S##11b[2]) \
    LPW(S, 7,  L##S##00b[3], L##S##10b[3], L##S##01b[3], L##S##11b[3]) \
    LPW(S, 8,  L##S##00c[0], L##S##10c[0], L##S##01c[0], L##S##11c[0]) \
    LPW(S, 9,  L##S##00c[1], L##S##10c[1], L##S##01c[1], L##S##11c[1]) \
    LPW(S, 10, L##S##00c[2], L##S##10c[2], L##S##01c[2], L##S##11c[2]) \
    LPW(S, 11, L##S##00c[3], L##S##10c[3], L##S##01c[3], L##S##11c[3]) }

#define TRIG(S) float pe##S[16]; \
    _Pragma("unroll") \
    for (int kf = 0; kf < NF; ++kf) { \
        const float fr = 6.28318530717958647692f * (float)(1 << kf); \
        float au = lu_pe##S * fr; \
        float av = lv_pe##S * fr; \
        pe##S[kf]          = __cosf(au); \
        pe##S[NF + kf]     = __sinf(au); \
        pe##S[2 * NF + kf] = __cosf(av); \
        pe##S[3 * NF + kf] = __sinf(av); }

#define FEATPACK(S) unsigned fd##S[16]; { \
    float feat[32]; \
    feat[0] = e0##S; feat[1] = e1##S; \
    _Pragma("unroll") \
    for (int q = 0; q < D0; ++q) feat[2 + q] = coeff##S[q]; \
    _Pragma("unroll") \
    for (int q = 0; q < 4 * NF; ++q) feat[2 + D0 + q] = coeff##S[D0 + q] * pe##S[q]; \
    _Pragma("unroll") \
    for (int q = 26; q < 32; ++q) feat[q] = 0.f; \
    _Pragma("unroll") \
    for (int i = 0; i < 16; ++i) fd##S[i] = pkbf(feat[2 * i], feat[2 * i + 1]); }

#define B0BUILD(S, DST) unsigned DST[2][2][4]; \
    _Pragma("unroll") \
    for (int ks = 0; ks < 2; ++ks) \
    _Pragma("unroll") \
        for (int j2 = 0; j2 < 4; ++j2) { \
            unsigned a_ = fd##S[8 * ks + j2]; \
            unsigned b_ = fd##S[8 * ks + 4 + j2]; \
            auto r_ = __builtin_amdgcn_permlane32_swap(b_, a_, false, false); \
            DST[ks][1][j2] = r_[0]; \
            DST[ks][0][j2] = r_[1]; }

// ---------- main kernel: single point/lane, bf16 grids; optional perm ----------
template<bool SORTED>
__global__ __launch_bounds__(256, 4)
void colornet_one(const float2* __restrict__ pts,
                  const unsigned* __restrict__ perm,
                  const float* __restrict__ ws,
                  const float* __restrict__ b2,
                  f32x4* __restrict__ out)
{
    const int lane = threadIdx.x & 63;
    const int wave = threadIdx.x >> 6;
    const int q5 = lane >> 5;
    int bid = blockIdx.x;
    if (SORTED) {
        // XCD-chunk swizzle: gridDim is a multiple of 8 -> bijective
        int cpx = gridDim.x >> 3;
        bid = (bid & 7) * cpx + (bid >> 3);
    }
    const int base_pt = bid * 256 + wave * 64;
    const char* wsb = (const char*)ws;
    const u32x4* LP = (const u32x4*)(wsb + LPE_OFF);

    float2 c = pts[base_pt + lane];
    float uA = fminf(fmaxf(c.x, 0.f), 1.f - 1e-6f);
    float vA = fminf(fmaxf(c.y, 0.f), 1.f - 1e-6f);

    float e0A = 0.f, e1A = 0.f;
    float coeffA[LPE_OUT];

    GA(A, 7, 2048) GA(A, 6, 1024) GA(A, 5, 512) GA(A, 4, 256)
    GA(A, 3, 128)  GA(A, 2, 64)   GA(A, 1, 32)  GA(A, 0, 16)

    GL(A, 7, 2048, G7_OFF)
    GL(A, 6, 1024, G6_OFF)
    GL(A, 5, 512,  G5_OFF)
    GL(A, 4, 256,  G4_OFF)
    GL(A, 3, 128,  G3_OFF)
    GL(A, 2, 64,   G2_OFF)
    GL(A, 1, 32,   G1_OFF)
    GL(A, 0, 16,   G0_OFF)

    LPEA(A)
    LPEL(A)
    TRIG(A)

    GS(A, 7) GS(A, 6) GS(A, 5) GS(A, 4) GS(A, 3) GS(A, 2) GS(A, 1) GS(A, 0)
    LPEC(A)

    FEATPACK(A)
    B0BUILD(A, B0a)

    f32x16 acc2[2];
    mlp_pair(B0a, ws, b2, lane, q5, acc2);

    if (lane < 32) {
#pragma unroll
        for (int n = 0; n < 2; ++n) {
            f32x4 o;
            o[0] = 1.f / (1.f + __expf(-acc2[n][0]));
            o[1] = 1.f / (1.f + __expf(-acc2[n][1]));
            o[2] = 1.f / (1.f + __expf(-acc2[n][2]));
            o[3] = 1.f / (1.f + __expf(-acc2[n][3]));
            int oi = base_pt + 32 * n + lane;
            if (SORTED) oi = (int)perm[oi];
            __builtin_nontemporal_store(o, out + oi);
        }
    }
}

// ---------- fp32 single-point fallback (R6-verified) ----------
template<int R>
__device__ __forceinline__ void gather_level(const float* __restrict__ g,
                                             float u, float v,
                                             float& e0, float& e1) {
    const float scale = (float)(R - 1);
    float fu = u * scale, fv = v * scale;
    int i0 = (int)floorf(fu);
    int j0 = (int)floorf(fv);
    i0 = i0 < 0 ? 0 : (i0 > R - 2 ? R - 2 : i0);
    j0 = j0 < 0 ? 0 : (j0 > R - 2 ? R - 2 : j0);
    float lu = fu - (float)i0;
    float lv = fv - (float)j0;
    const float2* gg = (const float2*)g;
    int base = i0 + j0 * R;
    float2 f00 = gg[base];
    float2 f10 = gg[base + 1];
    float2 f01 = gg[base + R];
    float2 f11 = gg[base + R + 1];
    float omu = 1.f - lu, omv = 1.f - lv;
    float w00 = omu * omv, w10 = lu * omv, w01 = omu * lv, w11 = lu * lv;
    e0 += f00.x * w00 + f10.x * w10 + f01.x * w01 + f11.x * w11;
    e1 += f00.y * w00 + f10.y * w10 + f01.y * w01 + f11.y * w11;
}

__global__ __launch_bounds__(256, 4)
void colornet_fp32(const float* __restrict__ coords,
                   const float* __restrict__ g0, const float* __restrict__ g1,
                   const float* __restrict__ g2, const float* __restrict__ g3,
                   const float* __restrict__ g4, const float* __restrict__ g5,
                   const float* __restrict__ g6, const float* __restrict__ g7,
                   const float* __restrict__ lpe,
                   const float* __restrict__ ws,
                   const float* __restrict__ b2,
                   f32x4* __restrict__ out)
{
    const int lane = threadIdx.x & 63;
    const int wave = threadIdx.x >> 6;
    const int q5 = lane >> 5;
    const int base_pt = blockIdx.x * 256 + wave * 64;
    const int point = base_pt + lane;

    const float* cp = coords + 2 * point;
    float cx = __builtin_nontemporal_load(cp);
    float cy = __builtin_nontemporal_load(cp + 1);
    float uA = fminf(fmaxf(cx, 0.f), 1.f - 1e-6f);
    float vA = fminf(fmaxf(cy, 0.f), 1.f - 1e-6f);

    float e0 = 0.f, e1 = 0.f;
    gather_level<16>(g0, uA, vA, e0, e1);
    gather_level<32>(g1, uA, vA, e0, e1);
    gather_level<64>(g2, uA, vA, e0, e1);
    gather_level<128>(g3, uA, vA, e0, e1);
    gather_level<256>(g4, uA, vA, e0, e1);
    gather_level<512>(g5, uA, vA, e0, e1);
    gather_level<1024>(g6, uA, vA, e0, e1);
    gather_level<2048>(g7, uA, vA, e0, e1);

    float coeff[LPE_OUT];
    float lu_pe, lv_pe;
    {
        float fu = uA * 128.f, fv = vA * 128.f;
        int i0 = (int)floorf(fu);
        int j0 = (int)floorf(fv);
        i0 = i0 < 0 ? 0 : (i0 > 127 ? 127 : i0);
        j0 = j0 < 0 ? 0 : (j0 > 127 ? 127 : j0);
        lu_pe = fu - (float)i0;
        lv_pe = fv - (float)j0;
        int base = (i0 + j0 * 129) * LPE_OUT;
        const float4* p00 = (const float4*)(lpe + base);
        const float4* p10 = (const float4*)(lpe + base + LPE_OUT);
        const float4* p01 = (const float4*)(lpe + base + 129 * LPE_OUT);
        const float4* p11 = (const float4*)(lpe + base + 130 * LPE_OUT);
        float omu = 1.f - lu_pe, omv = 1.f - lv_pe;
        float w00 = omu * omv, w10 = lu_pe * omv, w01 = omu * lv_pe, w11 = lu_pe * lv_pe;
#pragma unroll
        for (int q = 0; q < 6; ++q) {
            float4 a = p00[q], bq = p10[q], cq = p01[q], dq = p11[q];
            coeff[4 * q + 0] = a.x * w00 + bq.x * w10 + cq.x * w01 + dq.x * w11;
            coeff[4 * q + 1] = a.y * w00 + bq.y * w10 + cq.y * w01 + dq.y * w11;
            coeff[4 * q + 2] = a.z * w00 + bq.z * w10 + cq.z * w01 + dq.z * w11;
            coeff[4 * q + 3] = a.w * w00 + bq.w * w10 + cq.w * w01 + dq.w * w11;
        }
    }

    float pe[16];
#pragma unroll
    for (int kf = 0; kf < NF; ++kf) {
        const float fr = 6.28318530717958647692f * (float)(1 << kf);
        float au = lu_pe * fr;
        float av = lv_pe * fr;
        pe[kf]          = __cosf(au);
        pe[NF + kf]     = __sinf(au);
        pe[2 * NF + kf] = __cosf(av);
        pe[3 * NF + kf] = __sinf(av);
    }

    float feat[32];
    feat[0] = e0; feat[1] = e1;
#pragma unroll
    for (int q = 0; q < D0; ++q) feat[2 + q] = coeff[q];
#pragma unroll
    for (int q = 0; q < 4 * NF; ++q) feat[2 + D0 + q] = coeff[D0 + q] * pe[q];
#pragma unroll
    for (int q = 26; q < 32; ++q) feat[q] = 0.f;

    unsigned fd[16];
#pragma unroll
    for (int i = 0; i < 16; ++i) fd[i] = pkbf(feat[2 * i], feat[2 * i + 1]);

    unsigned B0[2][2][4];
#pragma unroll
    for (int ks = 0; ks < 2; ++ks)
#pragma unroll
        for (int j2 = 0; j2 < 4; ++j2) {
            unsigned a = fd[8 * ks + j2];
            unsigned b = fd[8 * ks + 4 + j2];
            auto r = __builtin_amdgcn_permlane32_swap(b, a, false, false);
            B0[ks][1][j2] = r[0];
            B0[ks][0][j2] = r[1];
        }

    f32x16 acc2[2];
    mlp_pair(B0, ws, b2, lane, q5, acc2);
    if (lane < 32) {
#pragma unroll
        for (int n = 0; n < 2; ++n) {
            f32x4 o;
            o[0] = 1.f / (1.f + __expf(-acc2[n][0]));
            o[1] = 1.f / (1.f + __expf(-acc2[n][1]));
            o[2] = 1.f / (1.f + __expf(-acc2[n][2]));
            o[3] = 1.f / (1.f + __expf(-acc2[n][3]));
            __builtin_nontemporal_store(o, out + (base_pt + 32 * n + lane));
        }
    }
}

extern "C" void kernel_launch(void* const* d_in, const int* in_sizes, int n_in,
                              void* d_out, int out_size, void* d_ws, size_t ws_size,
                              hipStream_t stream) {
    const float* coords = (const float*)d_in[0];
    const float* g0 = (const float*)d_in[1];
    const float* g1 = (const float*)d_in[2];
    const float* g2 = (const float*)d_in[3];
    const float* g3 = (const float*)d_in[4];
    const float* g4 = (const float*)d_in[5];
    const float* g5 = (const float*)d_in[6];
    const float* g6 = (const float*)d_in[7];
    const float* g7 = (const float*)d_in[8];
    const float* lpe = (const float*)d_in[9];
    const float* w0 = (const float*)d_in[10];
    const float* b0 = (const float*)d_in[11];
    const float* w1 = (const float*)d_in[12];
    const float* b1 = (const float*)d_in[13];
    const float* w2 = (const float*)d_in[14];
    const float* b2 = (const float*)d_in[15];
    f32x4* out = (f32x4*)d_out;

    int B = in_sizes[0] / 2;
    char* wsb = (char*)d_ws;

    prep_kernel<<<1, 256, 0, stream>>>(w0, b0, w1, b1, w2, (float*)d_ws);

    if (ws_size >= WS_NEED2 && B == 1048576) {
        conv_grids<<<21845, 256, 0, stream>>>((const float2*)g0, (const float2*)g1,
                                              (const float2*)g2, (const float2*)g3,
                                              (const float2*)g4, (const float2*)g5,
                                              (const float2*)g6, (const float2*)g7, wsb);
        conv_lpe<<<196, 256, 0, stream>>>((const float4*)lpe,
                                          (u32x4*)(wsb + LPE_OFF));

        unsigned* part   = (unsigned*)(wsb + PART_OFF);
        unsigned* totals = (unsigned*)(wsb + STARTS_OFF);
        unsigned* starts = totals + 256;
        float2*   scoord = (float2*)(wsb + SCOORD_OFF);
        unsigned* perm   = (unsigned*)(wsb + PERM_OFF);
        const float2* c2 = (const float2*)coords;

        sort_hist<<<4096, 256, 0, stream>>>(c2, part);
        sort_totals<<<256, 256, 0, stream>>>(part, totals);
        sort_starts<<<1, 256, 0, stream>>>(totals, starts);
        sort_offsets<<<256, 256, 0, stream>>>(part, starts);
        sort_scatter<<<4096, 256, 0, stream>>>(c2, part, scoord, perm);

        colornet_one<true><<<4096, 256, 0, stream>>>(scoord, perm,
                                                     (const float*)d_ws, b2, out);
    } else if (ws_size >= WS_NEED) {
        conv_grids<<<21845, 256, 0, stream>>>((const float2*)g0, (const float2*)g1,
                                              (const float2*)g2, (const float2*)g3,
                                              (const float2*)g4, (const float2*)g5,
                                              (const float2*)g6, (const float2*)g7, wsb);
        conv_lpe<<<196, 256, 0, stream>>>((const float4*)lpe,
                                          (u32x4*)(wsb + LPE_OFF));
        colornet_one<false><<<B / 256, 256, 0, stream>>>((const float2*)coords, nullptr,
                                                         (const float*)d_ws, b2, out);
    } else {
        colornet_fp32<<<B / 256, 256, 0, stream>>>(coords, g0, g1, g2, g3, g4, g5, g6, g7,
                                                   lpe, (const float*)d_ws, b2, out);
    }
}